// Round 1
// baseline (1139.000 us; speedup 1.0000x reference)
//
#include <hip/hip_runtime.h>

#define NCH 32          // channels
#define GROUPS 8        // float4 groups per row (32 / 4)
#define KVOL 27         // 3^3 kernel offsets

__global__ void mink_conv_scatter(const int* __restrict__ coords,
                                  const int* __restrict__ in_idx,
                                  const int* __restrict__ out_idx,
                                  const float4* __restrict__ in_feats4,
                                  const float4* __restrict__ kernel4,
                                  float* __restrict__ out,
                                  int E) {
    // Stage depthwise kernel (27 x 32 fp32 = 3456 B) into LDS once per block.
    __shared__ float4 kw[KVOL * GROUPS];
    for (int i = threadIdx.x; i < KVOL * GROUPS; i += blockDim.x) {
        kw[i] = kernel4[i];
    }
    __syncthreads();

    int t = blockIdx.x * blockDim.x + threadIdx.x;
    int total = E * GROUPS;
    if (t >= total) return;

    int e = t >> 3;      // edge index
    int g = t & 7;       // float4 group within the 32-channel row

    int vi = in_idx[e];
    int vo = out_idx[e];

    // k1d = (dx+1)*9 + (dy+1)*3 + (dz+1), from coords (L2-resident, 3.6 MB)
    int c0 = coords[vi * 3 + 0] - coords[vo * 3 + 0] + 1;
    int c1 = coords[vi * 3 + 1] - coords[vo * 3 + 1] + 1;
    int c2 = coords[vi * 3 + 2] - coords[vo * 3 + 2] + 1;
    int k1d = (c0 * 3 + c1) * 3 + c2;

    float4 f = in_feats4[vi * GROUPS + g];   // coalesced 128 B per 8 lanes
    float4 w = kw[k1d * GROUPS + g];

    float* o = out + vo * NCH + g * 4;
    atomicAdd(o + 0, f.x * w.x);
    atomicAdd(o + 1, f.y * w.y);
    atomicAdd(o + 2, f.z * w.z);
    atomicAdd(o + 3, f.w * w.w);
}

extern "C" void kernel_launch(void* const* d_in, const int* in_sizes, int n_in,
                              void* d_out, int out_size, void* d_ws, size_t ws_size,
                              hipStream_t stream) {
    const int*   coords   = (const int*)d_in[0];
    const int*   in_idx   = (const int*)d_in[1];
    const int*   out_idx  = (const int*)d_in[2];
    const float* in_feats = (const float*)d_in[3];
    const float* kernel   = (const float*)d_in[4];
    float*       out      = (float*)d_out;

    const int E = in_sizes[1];   // edge count

    // d_out is poisoned (0xAA) before every launch — zero it (capture-safe).
    hipMemsetAsync(d_out, 0, (size_t)out_size * sizeof(float), stream);

    int total = E * GROUPS;
    int block = 256;
    int grid  = (total + block - 1) / block;
    mink_conv_scatter<<<grid, block, 0, stream>>>(
        coords, in_idx, out_idx,
        (const float4*)in_feats, (const float4*)kernel,
        out, E);
}

// Round 2
// 246.607 us; speedup vs baseline: 4.6187x; 4.6187x over previous
//
#include <hip/hip_runtime.h>

#define NCH 32          // channels
#define GROUPS 8        // float4 groups per row (32 / 4)
#define KVOL 27         // 3^3 kernel offsets
#define ROWS_PER_BLOCK 32

// ---------------- Kernel 1: invert scatter into dense (out, offset) table ----
// For a fixed (out voxel, kernel offset) at most ONE input edge exists
// (coords are unique), so plain stores suffice — no atomics.
__global__ void build_table(const int* __restrict__ coords,
                            const int* __restrict__ in_idx,
                            const int* __restrict__ out_idx,
                            int* __restrict__ table,   // [N * 27], 0 = empty
                            int E) {
    int e = blockIdx.x * blockDim.x + threadIdx.x;
    if (e >= E) return;
    int vi = in_idx[e];
    int vo = out_idx[e];
    // k1d = (dx+1)*9 + (dy+1)*3 + (dz+1); coords (3.6 MB) stay L2-hot
    int c0 = coords[vi * 3 + 0] - coords[vo * 3 + 0] + 1;
    int c1 = coords[vi * 3 + 1] - coords[vo * 3 + 1] + 1;
    int c2 = coords[vi * 3 + 2] - coords[vo * 3 + 2] + 1;
    int k1d = (c0 * 3 + c1) * 3 + c2;
    table[(size_t)vo * KVOL + k1d] = vi + 1;
}

// ---------------- Kernel 2: per-output gather, atomic-free -------------------
// block = 256 threads = 32 output rows x 8 float4-groups.
__global__ void gather_conv(const int* __restrict__ table,
                            const float4* __restrict__ in_feats4,
                            const float4* __restrict__ kernel4,
                            float4* __restrict__ out4,
                            int Nrows) {
    __shared__ float4 kw[KVOL * GROUPS];        // 27x32 fp32 weights
    __shared__ int    tl[ROWS_PER_BLOCK * KVOL]; // 32x27 table slice

    for (int i = threadIdx.x; i < KVOL * GROUPS; i += blockDim.x)
        kw[i] = kernel4[i];

    int row0 = blockIdx.x * ROWS_PER_BLOCK;
    int nrow = min(ROWS_PER_BLOCK, Nrows - row0);
    int cnt  = nrow * KVOL;
    const int* tsrc = table + (size_t)row0 * KVOL;  // contiguous -> coalesced
    for (int i = threadIdx.x; i < cnt; i += blockDim.x)
        tl[i] = tsrc[i];
    __syncthreads();

    int lo = threadIdx.x >> 3;       // local row 0..31
    int g  = threadIdx.x & 7;        // float4 group 0..7
    int o  = row0 + lo;
    if (o >= Nrows) return;

    float4 acc = make_float4(0.f, 0.f, 0.f, 0.f);
    #pragma unroll
    for (int k = 0; k < KVOL; ++k) {
        int v = tl[lo * KVOL + k];   // lanes of same row broadcast; rows hit
                                     // distinct banks (27*{0..7} mod 32 unique)
        if (v > 0) {
            float4 f = in_feats4[(size_t)(v - 1) * GROUPS + g]; // 128B/row, coalesced per 8 lanes
            float4 w = kw[k * GROUPS + g];
            acc.x += f.x * w.x;
            acc.y += f.y * w.y;
            acc.z += f.z * w.z;
            acc.w += f.w * w.w;
        }
    }
    out4[(size_t)o * GROUPS + g] = acc;
}

// ---------------- Fallback (R1 atomic scatter) if ws is too small ------------
__global__ void mink_conv_scatter(const int* __restrict__ coords,
                                  const int* __restrict__ in_idx,
                                  const int* __restrict__ out_idx,
                                  const float4* __restrict__ in_feats4,
                                  const float4* __restrict__ kernel4,
                                  float* __restrict__ out,
                                  int E) {
    __shared__ float4 kw[KVOL * GROUPS];
    for (int i = threadIdx.x; i < KVOL * GROUPS; i += blockDim.x)
        kw[i] = kernel4[i];
    __syncthreads();
    int t = blockIdx.x * blockDim.x + threadIdx.x;
    if (t >= E * GROUPS) return;
    int e = t >> 3, g = t & 7;
    int vi = in_idx[e], vo = out_idx[e];
    int c0 = coords[vi * 3 + 0] - coords[vo * 3 + 0] + 1;
    int c1 = coords[vi * 3 + 1] - coords[vo * 3 + 1] + 1;
    int c2 = coords[vi * 3 + 2] - coords[vo * 3 + 2] + 1;
    int k1d = (c0 * 3 + c1) * 3 + c2;
    float4 f = in_feats4[vi * GROUPS + g];
    float4 w = kw[k1d * GROUPS + g];
    float* o = out + vo * NCH + g * 4;
    atomicAdd(o + 0, f.x * w.x);
    atomicAdd(o + 1, f.y * w.y);
    atomicAdd(o + 2, f.z * w.z);
    atomicAdd(o + 3, f.w * w.w);
}

extern "C" void kernel_launch(void* const* d_in, const int* in_sizes, int n_in,
                              void* d_out, int out_size, void* d_ws, size_t ws_size,
                              hipStream_t stream) {
    const int*   coords   = (const int*)d_in[0];
    const int*   in_idx   = (const int*)d_in[1];
    const int*   out_idx  = (const int*)d_in[2];
    const float* in_feats = (const float*)d_in[3];
    const float* kernel   = (const float*)d_in[4];

    const int E     = in_sizes[1];          // edge count
    const int Nrows = out_size / NCH;       // number of output voxels

    const size_t table_bytes = (size_t)Nrows * KVOL * sizeof(int);

    if (ws_size >= table_bytes) {
        int* table = (int*)d_ws;
        hipMemsetAsync(table, 0, table_bytes, stream);   // capture-safe

        int block = 256;
        int grid1 = (E + block - 1) / block;
        build_table<<<grid1, block, 0, stream>>>(coords, in_idx, out_idx, table, E);

        int grid2 = (Nrows + ROWS_PER_BLOCK - 1) / ROWS_PER_BLOCK;
        gather_conv<<<grid2, block, 0, stream>>>(
            table, (const float4*)in_feats, (const float4*)kernel,
            (float4*)d_out, Nrows);
    } else {
        // Fallback: atomic scatter (known-correct R1 path)
        hipMemsetAsync(d_out, 0, (size_t)out_size * sizeof(float), stream);
        int total = E * GROUPS;
        int block = 256;
        int grid  = (total + block - 1) / block;
        mink_conv_scatter<<<grid, block, 0, stream>>>(
            coords, in_idx, out_idx,
            (const float4*)in_feats, (const float4*)kernel,
            (float*)d_out, E);
    }
}

// Round 3
// 182.882 us; speedup vs baseline: 6.2281x; 1.3484x over previous
//
#include <hip/hip_runtime.h>

#define NCH 32          // channels
#define GROUPS 8        // float4 groups per row (32 / 4)
#define KVOL 27         // 3^3 kernel offsets
#define ROWS_PER_BLOCK 32
#define LG 100          // grid side
#define LP 102          // padded side (1-cell zero ring -> no bounds checks)

// ---- Kernel 1: build padded dense presence map: dense[flatp] = row+1 --------
// Coords are unique -> collision-free plain stores, no atomics.
__global__ void build_dense(const int* __restrict__ coords,
                            int* __restrict__ dense, int N) {
    int i = blockIdx.x * blockDim.x + threadIdx.x;
    if (i >= N) return;
    int x = coords[3 * i + 0];
    int y = coords[3 * i + 1];
    int z = coords[3 * i + 2];
    int f = ((x + 1) * LP + (y + 1)) * LP + (z + 1);
    dense[f] = i + 1;
}

// ---- Kernel 2: per-output gather via dense-map lookups, atomic-free ---------
// block = 256 threads = 32 output rows x 8 float4-groups.
__global__ void gather_conv(const int* __restrict__ coords,
                            const int* __restrict__ dense,
                            const float4* __restrict__ in_feats4,
                            const float4* __restrict__ kernel4,
                            float4* __restrict__ out4,
                            int Nrows) {
    __shared__ float4 kw[KVOL * GROUPS];          // 27x32 fp32 weights
    __shared__ int    nb[ROWS_PER_BLOCK * KVOL];  // neighbor row+1 (0 = none)
    __shared__ int    base[ROWS_PER_BLOCK];       // padded flat index per row

    for (int i = threadIdx.x; i < KVOL * GROUPS; i += blockDim.x)
        kw[i] = kernel4[i];

    int row0 = blockIdx.x * ROWS_PER_BLOCK;
    int nrow = min(ROWS_PER_BLOCK, Nrows - row0);

    if (threadIdx.x < nrow) {
        int o = row0 + threadIdx.x;
        int x = coords[3 * o + 0];
        int y = coords[3 * o + 1];
        int z = coords[3 * o + 2];
        base[threadIdx.x] = ((x + 1) * LP + (y + 1)) * LP + (z + 1);
    }
    __syncthreads();

    // Cooperative neighbor lookups: 32*27 = 864 random 4B loads into 4.25 MB
    // (L2-resident) padded map. Pad ring is 0 -> no bounds checks needed.
    int cnt = nrow * KVOL;
    for (int i = threadIdx.x; i < cnt; i += blockDim.x) {
        int lo = i / KVOL;           // const divisor -> magic mul
        int k  = i - lo * KVOL;
        int dx = k / 9;
        int r  = k - dx * 9;
        int dy = r / 3;
        int dz = r - dy * 3;
        int off = (dx - 1) * (LP * LP) + (dy - 1) * LP + (dz - 1);
        nb[i] = dense[base[lo] + off];
    }
    __syncthreads();

    int lo = threadIdx.x >> 3;       // local row 0..31
    int g  = threadIdx.x & 7;        // float4 group 0..7
    int o  = row0 + lo;
    if (o >= Nrows) return;

    float4 acc = make_float4(0.f, 0.f, 0.f, 0.f);
    #pragma unroll
    for (int k = 0; k < KVOL; ++k) {
        int v = nb[lo * KVOL + k];
        if (v > 0) {
            float4 f = in_feats4[(size_t)(v - 1) * GROUPS + g]; // 128B/row
            float4 w = kw[k * GROUPS + g];
            acc.x += f.x * w.x;
            acc.y += f.y * w.y;
            acc.z += f.z * w.z;
            acc.w += f.w * w.w;
        }
    }
    out4[(size_t)o * GROUPS + g] = acc;
}

// ---- Fallback (R1 atomic scatter) if ws is too small ------------------------
__global__ void mink_conv_scatter(const int* __restrict__ coords,
                                  const int* __restrict__ in_idx,
                                  const int* __restrict__ out_idx,
                                  const float4* __restrict__ in_feats4,
                                  const float4* __restrict__ kernel4,
                                  float* __restrict__ out,
                                  int E) {
    __shared__ float4 kw[KVOL * GROUPS];
    for (int i = threadIdx.x; i < KVOL * GROUPS; i += blockDim.x)
        kw[i] = kernel4[i];
    __syncthreads();
    int t = blockIdx.x * blockDim.x + threadIdx.x;
    if (t >= E * GROUPS) return;
    int e = t >> 3, g = t & 7;
    int vi = in_idx[e], vo = out_idx[e];
    int c0 = coords[vi * 3 + 0] - coords[vo * 3 + 0] + 1;
    int c1 = coords[vi * 3 + 1] - coords[vo * 3 + 1] + 1;
    int c2 = coords[vi * 3 + 2] - coords[vo * 3 + 2] + 1;
    int k1d = (c0 * 3 + c1) * 3 + c2;
    float4 f = in_feats4[vi * GROUPS + g];
    float4 w = kw[k1d * GROUPS + g];
    float* o = out + vo * NCH + g * 4;
    atomicAdd(o + 0, f.x * w.x);
    atomicAdd(o + 1, f.y * w.y);
    atomicAdd(o + 2, f.z * w.z);
    atomicAdd(o + 3, f.w * w.w);
}

extern "C" void kernel_launch(void* const* d_in, const int* in_sizes, int n_in,
                              void* d_out, int out_size, void* d_ws, size_t ws_size,
                              hipStream_t stream) {
    const int*   coords   = (const int*)d_in[0];
    const int*   in_idx   = (const int*)d_in[1];
    const int*   out_idx  = (const int*)d_in[2];
    const float* in_feats = (const float*)d_in[3];
    const float* kernel   = (const float*)d_in[4];

    const int E     = in_sizes[1];          // edge count
    const int Nrows = out_size / NCH;       // number of output voxels

    const size_t dense_bytes = (size_t)LP * LP * LP * sizeof(int); // 4.25 MB

    if (ws_size >= dense_bytes) {
        int* dense = (int*)d_ws;
        hipMemsetAsync(dense, 0, dense_bytes, stream);   // capture-safe

        int block = 256;
        int grid1 = (Nrows + block - 1) / block;
        build_dense<<<grid1, block, 0, stream>>>(coords, dense, Nrows);

        int grid2 = (Nrows + ROWS_PER_BLOCK - 1) / ROWS_PER_BLOCK;
        gather_conv<<<grid2, block, 0, stream>>>(
            coords, dense, (const float4*)in_feats, (const float4*)kernel,
            (float4*)d_out, Nrows);
    } else {
        // Fallback: atomic scatter (known-correct R1 path)
        hipMemsetAsync(d_out, 0, (size_t)out_size * sizeof(float), stream);
        int total = E * GROUPS;
        int block = 256;
        int grid  = (total + block - 1) / block;
        mink_conv_scatter<<<grid, block, 0, stream>>>(
            coords, in_idx, out_idx,
            (const float4*)in_feats, (const float4*)kernel,
            (float*)d_out, E);
    }
}

// Round 4
// 174.645 us; speedup vs baseline: 6.5218x; 1.0472x over previous
//
#include <hip/hip_runtime.h>

#define NCH 32          // channels
#define GROUPS 8        // float4 groups per row (32 / 4)
#define KVOL 27         // 3^3 kernel offsets
#define LG 100          // grid side
#define LP 102          // padded side (1-cell zero ring)
#define RGN 4           // region side per block
#define NRGN 25         // LG / RGN
#define NREGIONS (NRGN * NRGN * NRGN)   // 15625
#define BVOL 216        // (RGN+2)^3 brick cells

// ---- Kernel 1: padded dense presence map: dense[flatp] = row+1 --------------
__global__ void build_dense(const int* __restrict__ coords,
                            int* __restrict__ dense, int N) {
    int i = blockIdx.x * blockDim.x + threadIdx.x;
    if (i >= N) return;
    int x = coords[3 * i + 0];
    int y = coords[3 * i + 1];
    int z = coords[3 * i + 2];
    dense[((size_t)(x + 1) * LP + (y + 1)) * LP + (z + 1)] = i + 1;
}

// ---- Kernel 2: spatial-region gather --------------------------------------
// One block = one 4x4x4 region of the grid. Brick (6^3 presence) in LDS.
__global__ __launch_bounds__(256) void gather_conv_region(
        const int* __restrict__ dense,
        const float4* __restrict__ in_feats4,
        const float4* __restrict__ kernel4,
        float4* __restrict__ out4) {
    __shared__ float4 kw[KVOL * GROUPS];   // 27x32 weights (3456 B)
    __shared__ int brick[BVOL];            // 6x6x6 presence (row+1, 0=empty)
    __shared__ int rows[RGN * RGN * RGN];  // compacted occupied rows
    __shared__ int rbid[RGN * RGN * RGN];  // their brick index
    __shared__ int cnt;

    int tid = threadIdx.x;

    // XCD slab swizzle: blocks b with b&7==x (presumed XCD x via round-robin)
    // get the contiguous region slab [x*per, ...) -> halo reuse stays in-XCD.
    int b = blockIdx.x;
    const int per = (NREGIONS + 7) >> 3;   // 1954
    int r = (b & 7) * per + (b >> 3);
    if (r >= NREGIONS) return;             // uniform per block - safe

    if (tid == 0) cnt = 0;
    for (int i = tid; i < KVOL * GROUPS; i += 256) kw[i] = kernel4[i];

    int bx = r / (NRGN * NRGN);
    int by = (r / NRGN) % NRGN;
    int bz = r % NRGN;
    int ox = bx * RGN, oy = by * RGN, oz = bz * RGN;  // brick origin (padded)

    // Load 6x6x6 brick of the dense map (region + halo). 216 x 4B, L2-hot.
    for (int i = tid; i < BVOL; i += 256) {
        int lx = i / 36, ly = (i / 6) % 6, lz = i % 6;
        brick[i] = dense[((size_t)(ox + lx) * LP + (oy + ly)) * LP + (oz + lz)];
    }
    __syncthreads();

    // Compact occupied interior cells (order within block irrelevant).
    if (tid < RGN * RGN * RGN) {
        int cx = tid >> 4, cy = (tid >> 2) & 3, cz = tid & 3;
        int bidx = (cx + 1) * 36 + (cy + 1) * 6 + (cz + 1);
        int v = brick[bidx];
        if (v > 0) {
            int p = atomicAdd(&cnt, 1);
            rows[p] = v - 1;
            rbid[p] = bidx;
        }
    }
    __syncthreads();

    int n  = cnt;
    int lr = tid >> 3;       // 0..31: row slot
    int g  = tid & 7;        // float4 group
    for (int base = 0; base < n; base += 32) {
        int lo = base + lr;
        if (lo < n) {
            int row  = rows[lo];
            int bidx = rbid[lo];
            float4 acc = make_float4(0.f, 0.f, 0.f, 0.f);
            #pragma unroll
            for (int k = 0; k < KVOL; ++k) {    // tap offsets fold to constants
                int dx = k / 9 - 1, dy = (k / 3) % 3 - 1, dz = k % 3 - 1;
                int v = brick[bidx + dx * 36 + dy * 6 + dz];
                if (v > 0) {
                    float4 f = in_feats4[(size_t)(v - 1) * GROUPS + g];
                    float4 w = kw[k * GROUPS + g];
                    acc.x += f.x * w.x;
                    acc.y += f.y * w.y;
                    acc.z += f.z * w.z;
                    acc.w += f.w * w.w;
                }
            }
            out4[(size_t)row * GROUPS + g] = acc;   // scattered 128B store
        }
    }
}

// ---- Fallback (R1 atomic scatter) if ws is too small ------------------------
__global__ void mink_conv_scatter(const int* __restrict__ coords,
                                  const int* __restrict__ in_idx,
                                  const int* __restrict__ out_idx,
                                  const float4* __restrict__ in_feats4,
                                  const float4* __restrict__ kernel4,
                                  float* __restrict__ out,
                                  int E) {
    __shared__ float4 kw[KVOL * GROUPS];
    for (int i = threadIdx.x; i < KVOL * GROUPS; i += blockDim.x)
        kw[i] = kernel4[i];
    __syncthreads();
    int t = blockIdx.x * blockDim.x + threadIdx.x;
    if (t >= E * GROUPS) return;
    int e = t >> 3, g = t & 7;
    int vi = in_idx[e], vo = out_idx[e];
    int c0 = coords[vi * 3 + 0] - coords[vo * 3 + 0] + 1;
    int c1 = coords[vi * 3 + 1] - coords[vo * 3 + 1] + 1;
    int c2 = coords[vi * 3 + 2] - coords[vo * 3 + 2] + 1;
    int k1d = (c0 * 3 + c1) * 3 + c2;
    float4 f = in_feats4[vi * GROUPS + g];
    float4 w = kw[k1d * GROUPS + g];
    float* o = out + vo * NCH + g * 4;
    atomicAdd(o + 0, f.x * w.x);
    atomicAdd(o + 1, f.y * w.y);
    atomicAdd(o + 2, f.z * w.z);
    atomicAdd(o + 3, f.w * w.w);
}

extern "C" void kernel_launch(void* const* d_in, const int* in_sizes, int n_in,
                              void* d_out, int out_size, void* d_ws, size_t ws_size,
                              hipStream_t stream) {
    const int*   coords   = (const int*)d_in[0];
    const int*   in_idx   = (const int*)d_in[1];
    const int*   out_idx  = (const int*)d_in[2];
    const float* in_feats = (const float*)d_in[3];
    const float* kernel   = (const float*)d_in[4];

    const int E     = in_sizes[1];
    const int Nrows = out_size / NCH;

    const size_t dense_bytes = (size_t)LP * LP * LP * sizeof(int); // 4.25 MB

    if (ws_size >= dense_bytes) {
        int* dense = (int*)d_ws;
        hipMemsetAsync(dense, 0, dense_bytes, stream);

        int block = 256;
        int grid1 = (Nrows + block - 1) / block;
        build_dense<<<grid1, block, 0, stream>>>(coords, dense, Nrows);

        const int per = (NREGIONS + 7) >> 3;
        int grid2 = per * 8;                 // swizzled; excess blocks return
        gather_conv_region<<<grid2, 256, 0, stream>>>(
            dense, (const float4*)in_feats, (const float4*)kernel,
            (float4*)d_out);
    } else {
        hipMemsetAsync(d_out, 0, (size_t)out_size * sizeof(float), stream);
        int total = E * GROUPS;
        int block = 256;
        int grid  = (total + block - 1) / block;
        mink_conv_scatter<<<grid, block, 0, stream>>>(
            coords, in_idx, out_idx,
            (const float4*)in_feats, (const float4*)kernel,
            (float*)d_out, E);
    }
}

// Round 5
// 144.200 us; speedup vs baseline: 7.8988x; 1.2111x over previous
//
#include <hip/hip_runtime.h>

#define NCH 32          // channels
#define GROUPS 8        // float4 groups per row (32 / 4)
#define KVOL 27         // 3^3 kernel offsets
#define LG 100          // grid side
#define LP 102          // padded side (1-cell zero ring)
#define RGN 5           // region side per block
#define NRGN 20         // LG / RGN
#define NREGIONS (NRGN * NRGN * NRGN)   // 8000
#define BSIDE 7         // RGN + 2
#define BVOL 343        // brick cells
#define CELLS 125       // RGN^3
#define LSTR 29         // tap-list stride (odd -> LDS conflict-free, >= 28)

// ---- Kernel 1: padded dense presence map: dense[flatp] = row+1 --------------
__global__ void build_dense(const int* __restrict__ coords,
                            int* __restrict__ dense, int N) {
    int i = blockIdx.x * blockDim.x + threadIdx.x;
    if (i >= N) return;
    int x = coords[3 * i + 0];
    int y = coords[3 * i + 1];
    int z = coords[3 * i + 2];
    dense[((size_t)(x + 1) * LP + (y + 1)) * LP + (z + 1)] = i + 1;
}

// ---- Kernel 2: spatial-region gather, branchless batched inner loop ---------
__global__ __launch_bounds__(256) void gather_conv_region(
        const int* __restrict__ dense,
        const float4* __restrict__ in_feats4,
        const float4* __restrict__ kernel4,
        float4* __restrict__ out4) {
    __shared__ float4 kw[(KVOL + 1) * GROUPS]; // 28th row = zeros (dummy taps)
    __shared__ int brick[BVOL];                // 7^3 presence (row+1, 0=empty)
    __shared__ int rows[CELLS];                // compacted occupied feat rows
    __shared__ int cnts[CELLS];                // padded tap count per slot
    __shared__ int list[CELLS * LSTR];         // packed taps: (vrow<<5)|k
    __shared__ int cnt;

    int tid = threadIdx.x;

    // XCD slab swizzle: b&7 -> XCD (round-robin dispatch assumption, perf-only)
    int b = blockIdx.x;
    const int per = NREGIONS >> 3;             // 1000
    int r = (b & 7) * per + (b >> 3);

    if (tid == 0) cnt = 0;
    for (int i = tid; i < (KVOL + 1) * GROUPS; i += 256)
        kw[i] = (i < KVOL * GROUPS) ? kernel4[i]
                                    : make_float4(0.f, 0.f, 0.f, 0.f);

    int bx = r / (NRGN * NRGN);
    int by = (r / NRGN) % NRGN;
    int bz = r % NRGN;
    int ox = bx * RGN, oy = by * RGN, oz = bz * RGN;  // brick origin (padded)

    // Load 7x7x7 brick of the dense map (region + halo); L2-hot (4.25 MB map).
    for (int i = tid; i < BVOL; i += 256) {
        int lx = i / (BSIDE * BSIDE), ly = (i / BSIDE) % BSIDE, lz = i % BSIDE;
        brick[i] = dense[((size_t)(ox + lx) * LP + (oy + ly)) * LP + (oz + lz)];
    }
    __syncthreads();

    // Compaction: each occupied interior cell emits its valid taps (packed),
    // padded to a multiple of 4 with dummy taps (k=27 -> zero weight).
    if (tid < CELLS) {
        int cx = tid / (RGN * RGN), cy = (tid / RGN) % RGN, cz = tid % RGN;
        int bidx = (cx + 1) * (BSIDE * BSIDE) + (cy + 1) * BSIDE + (cz + 1);
        int v = brick[bidx];
        if (v > 0) {
            int p = atomicAdd(&cnt, 1);
            int myrow = v - 1;
            rows[p] = myrow;
            int j = 0;
            #pragma unroll
            for (int k = 0; k < KVOL; ++k) {   // folds to const brick offsets
                int dx = k / 9 - 1, dy = (k / 3) % 3 - 1, dz = k % 3 - 1;
                int nb = brick[bidx + dx * (BSIDE * BSIDE) + dy * BSIDE + dz];
                if (nb > 0) list[p * LSTR + (j++)] = ((nb - 1) << 5) | k;
            }
            while (j & 3) list[p * LSTR + (j++)] = (myrow << 5) | KVOL;
            cnts[p] = j;
        }
    }
    __syncthreads();

    int n  = cnt;
    int lr = tid >> 3;       // row slot 0..31
    int g  = tid & 7;        // float4 group
    for (int base = 0; base < n; base += 32) {
        int lo = base + lr;
        if (lo < n) {
            int cr = cnts[lo];
            const int* tl = &list[lo * LSTR];
            float4 acc = make_float4(0.f, 0.f, 0.f, 0.f);
            for (int j = 0; j < cr; j += 4) {  // 4 independent loads per step
                int e0 = tl[j + 0], e1 = tl[j + 1];
                int e2 = tl[j + 2], e3 = tl[j + 3];
                float4 f0 = in_feats4[(size_t)(e0 >> 5) * GROUPS + g];
                float4 f1 = in_feats4[(size_t)(e1 >> 5) * GROUPS + g];
                float4 f2 = in_feats4[(size_t)(e2 >> 5) * GROUPS + g];
                float4 f3 = in_feats4[(size_t)(e3 >> 5) * GROUPS + g];
                float4 w0 = kw[(e0 & 31) * GROUPS + g];
                float4 w1 = kw[(e1 & 31) * GROUPS + g];
                float4 w2 = kw[(e2 & 31) * GROUPS + g];
                float4 w3 = kw[(e3 & 31) * GROUPS + g];
                acc.x += f0.x * w0.x; acc.y += f0.y * w0.y;
                acc.z += f0.z * w0.z; acc.w += f0.w * w0.w;
                acc.x += f1.x * w1.x; acc.y += f1.y * w1.y;
                acc.z += f1.z * w1.z; acc.w += f1.w * w1.w;
                acc.x += f2.x * w2.x; acc.y += f2.y * w2.y;
                acc.z += f2.z * w2.z; acc.w += f2.w * w2.w;
                acc.x += f3.x * w3.x; acc.y += f3.y * w3.y;
                acc.z += f3.z * w3.z; acc.w += f3.w * w3.w;
            }
            out4[(size_t)rows[lo] * GROUPS + g] = acc;
        }
    }
}

// ---- Fallback (R1 atomic scatter) if ws is too small ------------------------
__global__ void mink_conv_scatter(const int* __restrict__ coords,
                                  const int* __restrict__ in_idx,
                                  const int* __restrict__ out_idx,
                                  const float4* __restrict__ in_feats4,
                                  const float4* __restrict__ kernel4,
                                  float* __restrict__ out,
                                  int E) {
    __shared__ float4 kw[KVOL * GROUPS];
    for (int i = threadIdx.x; i < KVOL * GROUPS; i += blockDim.x)
        kw[i] = kernel4[i];
    __syncthreads();
    int t = blockIdx.x * blockDim.x + threadIdx.x;
    if (t >= E * GROUPS) return;
    int e = t >> 3, g = t & 7;
    int vi = in_idx[e], vo = out_idx[e];
    int c0 = coords[vi * 3 + 0] - coords[vo * 3 + 0] + 1;
    int c1 = coords[vi * 3 + 1] - coords[vo * 3 + 1] + 1;
    int c2 = coords[vi * 3 + 2] - coords[vo * 3 + 2] + 1;
    int k1d = (c0 * 3 + c1) * 3 + c2;
    float4 f = in_feats4[vi * GROUPS + g];
    float4 w = kw[k1d * GROUPS + g];
    float* o = out + vo * NCH + g * 4;
    atomicAdd(o + 0, f.x * w.x);
    atomicAdd(o + 1, f.y * w.y);
    atomicAdd(o + 2, f.z * w.z);
    atomicAdd(o + 3, f.w * w.w);
}

extern "C" void kernel_launch(void* const* d_in, const int* in_sizes, int n_in,
                              void* d_out, int out_size, void* d_ws, size_t ws_size,
                              hipStream_t stream) {
    const int*   coords   = (const int*)d_in[0];
    const int*   in_idx   = (const int*)d_in[1];
    const int*   out_idx  = (const int*)d_in[2];
    const float* in_feats = (const float*)d_in[3];
    const float* kernel   = (const float*)d_in[4];

    const int E     = in_sizes[1];
    const int Nrows = out_size / NCH;

    const size_t dense_bytes = (size_t)LP * LP * LP * sizeof(int); // 4.25 MB

    if (ws_size >= dense_bytes) {
        int* dense = (int*)d_ws;
        hipMemsetAsync(dense, 0, dense_bytes, stream);

        int block = 256;
        int grid1 = (Nrows + block - 1) / block;
        build_dense<<<grid1, block, 0, stream>>>(coords, dense, Nrows);

        gather_conv_region<<<NREGIONS, 256, 0, stream>>>(
            dense, (const float4*)in_feats, (const float4*)kernel,
            (float4*)d_out);
    } else {
        hipMemsetAsync(d_out, 0, (size_t)out_size * sizeof(float), stream);
        int total = E * GROUPS;
        int block = 256;
        int grid  = (total + block - 1) / block;
        mink_conv_scatter<<<grid, block, 0, stream>>>(
            coords, in_idx, out_idx,
            (const float4*)in_feats, (const float4*)kernel,
            (float*)d_out, E);
    }
}